// Round 18
// baseline (129.199 us; speedup 1.0000x reference)
//
#include <hip/hip_runtime.h>
#include <hip/hip_bf16.h>
#include <cstdint>
#include <cstddef>

#define D_MODEL 1024
#define NHEADS  16
#define HDIM    64
#define BB      2
#define TT      2048
#define MM      (BB*TT)   // 4096 rows total

typedef __attribute__((ext_vector_type(8)))  short    bf16x8;
typedef __attribute__((ext_vector_type(4)))  float    f32x4;
typedef __attribute__((ext_vector_type(16))) float    f32x16;
typedef __attribute__((ext_vector_type(4)))  unsigned u32x4;
typedef unsigned short u16;

// fold 1/sqrt(64) * log2(e) into Q so softmax is p = exp2(s) directly
#define QSCALE 0.1803368801111204f

// ---- helpers ---------------------------------------------------------------

static __device__ __forceinline__ u16 f2bf(float f) {
  unsigned u = __builtin_bit_cast(unsigned, f);
  return (u16)((u + 0x7FFFu + ((u >> 16) & 1u)) >> 16);
}

static __device__ __forceinline__ void async16(const void* g, void* l) {
  __builtin_amdgcn_global_load_lds(
      (__attribute__((address_space(1))) void*)g,
      (__attribute__((address_space(3))) void*)l, 16, 0, 0);
}

// packed f32x2 -> bf16x2 (RNE), low word = first arg (compiler-lowered)
static __device__ __forceinline__ unsigned cvtpk(float lo, float hi) {
  __hip_bfloat162 h = __float22bfloat162_rn(float2{lo, hi});
  unsigned r;
  __builtin_memcpy(&r, &h, 4);
  return r;
}

// ---- fused f32 -> bf16 convert over all 7 inputs (one launch) --------------

#define NX8 (524288)   // NX/8
#define NW8 (131072)   // NW/8

__global__ __launch_bounds__(256) void cvt_all_kernel(
    const float* __restrict__ q, const float* __restrict__ k,
    const float* __restrict__ v, const float* __restrict__ wq,
    const float* __restrict__ wk, const float* __restrict__ wv,
    const float* __restrict__ wo, u16* __restrict__ dst, int n8) {
  int i = blockIdx.x * 256 + threadIdx.x;
  int stride = gridDim.x * 256;
  for (; i < n8; i += stride) {
    size_t j = (size_t)i;
    const float* s;
    if (j < NX8)            { s = q; }
    else if (j < 2 * NX8)   { s = k;  j -= NX8; }
    else if (j < 3 * NX8)   { s = v;  j -= 2 * (size_t)NX8; }
    else {
      j -= 3 * (size_t)NX8;
      if (j < NW8)          { s = wq; }
      else if (j < 2 * NW8) { s = wk; j -= NW8; }
      else if (j < 3 * NW8) { s = wv; j -= 2 * (size_t)NW8; }
      else                  { s = wo; j -= 3 * (size_t)NW8; }
    }
    float4 a = ((const float4*)s)[2 * j];
    float4 b = ((const float4*)s)[2 * j + 1];
    ushort4 ra, rb;
    ra.x = f2bf(a.x); ra.y = f2bf(a.y); ra.z = f2bf(a.z); ra.w = f2bf(a.w);
    rb.x = f2bf(b.x); rb.y = f2bf(b.y); rb.z = f2bf(b.z); rb.w = f2bf(b.w);
    ((ushort4*)dst)[2 * (size_t)i]     = ra;
    ((ushort4*)dst)[2 * (size_t)i + 1] = rb;
  }
}

// ---- GEMM core: C[128,128] tile of A[M,K] * W[N,K]^T (bf16, fp32 acc) ------
// r15 structure (best known): BK=64 dbuf, prefetch-before-MFMA, ONE barrier
// per K-step, T2 XOR-swizzle via pre-swizzled global source (rule #21-safe).

static __device__ __forceinline__ void gemm_core_1024(
    const u16* __restrict__ A, const u16* __restrict__ W,
    int m0, int n0, f32x4 acc[4][4],
    u16 (*__restrict__ sA)[128 * 64], u16 (*__restrict__ sB)[128 * 64]) {
  const int tid  = threadIdx.x;
  const int lane = tid & 63;
  const int wave = tid >> 6;
  const int wr = wave >> 1, wc = wave & 1;
  const int l16 = lane & 15, lq = lane >> 4;
  const int sx  = l16 & 7;                     // read-side row&7

  int rowi[4], cof[4];
#pragma unroll
  for (int i = 0; i < 4; ++i) {
    int idx = i * 256 + tid;
    rowi[i] = idx >> 3;
    cof[i]  = (((idx & 7) ^ (rowi[i] & 7)) << 3);   // u16 offset of 16B chunk
  }

  const int rc0 = ((0 * 4 + lq) ^ sx) << 3;
  const int rc1 = ((1 * 4 + lq) ^ sx) << 3;

  // prologue: stage K-tile 0 into buffer 0
#pragma unroll
  for (int i = 0; i < 4; ++i) {
    int idx = i * 256 + tid;
    async16(A + (size_t)(m0 + rowi[i]) * D_MODEL + cof[i], sA[0] + idx * 8);
    async16(W + (size_t)(n0 + rowi[i]) * D_MODEL + cof[i], sB[0] + idx * 8);
  }
  __syncthreads();   // vmcnt(0): buffer 0 ready

  int cur = 0;
  for (int k0 = 0; k0 < D_MODEL; k0 += 64) {
    if (k0 + 64 < D_MODEL) {
#pragma unroll
      for (int i = 0; i < 4; ++i) {
        int idx = i * 256 + tid;
        async16(A + (size_t)(m0 + rowi[i]) * D_MODEL + k0 + 64 + cof[i], sA[cur ^ 1] + idx * 8);
        async16(W + (size_t)(n0 + rowi[i]) * D_MODEL + k0 + 64 + cof[i], sB[cur ^ 1] + idx * 8);
      }
    }
    const u16* a_ = sA[cur];
    const u16* b_ = sB[cur];
#pragma unroll
    for (int ks = 0; ks < 2; ++ks) {
      const int rc = ks ? rc1 : rc0;
      bf16x8 af[4], bfr[4];
#pragma unroll
      for (int mi = 0; mi < 4; ++mi)
        af[mi] = *(const bf16x8*)(a_ + (wr*64 + mi*16 + l16)*64 + rc);
#pragma unroll
      for (int ni = 0; ni < 4; ++ni)
        bfr[ni] = *(const bf16x8*)(b_ + (wc*64 + ni*16 + l16)*64 + rc);
#pragma unroll
      for (int mi = 0; mi < 4; ++mi)
#pragma unroll
        for (int ni = 0; ni < 4; ++ni)
          acc[mi][ni] = __builtin_amdgcn_mfma_f32_16x16x32_bf16(
              af[mi], bfr[ni], acc[mi][ni], 0, 0, 0);
    }
    __syncthreads();
    cur ^= 1;
  }
}

// ---- fused QKV projection --------------------------------------------------
// Q gets QSCALE folded in. V written transposed [b][n][s'] with s' =
// swap-bits-2/3(s): bakes attn's PV slot order sigma into the layout so
// attn reads V fragments as single b128 (zero-exchange P path, no marshal).
// XCD-chunked swizzle (768 blocks, 96/XCD): W panels become L2-local (T1).

__global__ __launch_bounds__(256) void qkv_gemm(
    const u16* __restrict__ xq, const u16* __restrict__ xk, const u16* __restrict__ xv,
    const u16* __restrict__ wq, const u16* __restrict__ wk, const u16* __restrict__ wv,
    const float* __restrict__ bq, const float* __restrict__ bk, const float* __restrict__ bv,
    u16* __restrict__ Qo, u16* __restrict__ Ko, u16* __restrict__ Vt) {
  __shared__ __align__(16) u16 sA[2][128 * 64];
  __shared__ __align__(16) u16 sB[2][128 * 64];
  const int bid = (blockIdx.x & 7) * 96 + (blockIdx.x >> 3);   // bijective, 768%8==0
  const int mt = bid & 31, ct = bid >> 5;
  const int which = ct >> 3, nt = ct & 7;
  const u16* A = (which == 0) ? xq : (which == 1) ? xk : xv;
  const u16* W = (which == 0) ? wq : (which == 1) ? wk : wv;
  const float* bias = (which == 0) ? bq : (which == 1) ? bk : bv;
  const int m0 = mt * 128, n0 = nt * 128;

  f32x4 acc[4][4];
#pragma unroll
  for (int mi = 0; mi < 4; ++mi)
#pragma unroll
    for (int ni = 0; ni < 4; ++ni)
      acc[mi][ni] = f32x4{0.f, 0.f, 0.f, 0.f};

  gemm_core_1024(A, W, m0, n0, acc, sA, sB);

  const int lane = threadIdx.x & 63, wave = threadIdx.x >> 6;
  const int wr = wave >> 1, wc = wave & 1, l16 = lane & 15, lq = lane >> 4;
  const float qs = (which == 0) ? QSCALE : 1.0f;
#pragma unroll
  for (int mi = 0; mi < 4; ++mi) {
#pragma unroll
    for (int ni = 0; ni < 4; ++ni) {
      int n = n0 + wc*64 + ni*16 + l16;
      float bz = bias[n];
      int mb = m0 + wr*64 + mi*16 + lq*4;
      if (which == 2) {
        int b = mb >> 11, s = mb & 2047;
        int s2 = (s & ~0xC) | ((s & 4) << 1) | ((s & 8) >> 1);   // swap bits 2<->3
        ushort4 pk;
        pk.x = f2bf(acc[mi][ni][0] + bz);
        pk.y = f2bf(acc[mi][ni][1] + bz);
        pk.z = f2bf(acc[mi][ni][2] + bz);
        pk.w = f2bf(acc[mi][ni][3] + bz);
        *(ushort4*)(Vt + (size_t)(b * 1024 + n) * 2048 + s2) = pk;
      } else {
        u16* O = (which == 0) ? Qo : Ko;
#pragma unroll
        for (int j = 0; j < 4; ++j)
          O[(size_t)(mb + j) * D_MODEL + n] = f2bf((acc[mi][ni][j] + bz) * qs);
      }
    }
  }
}

// ---- flash attention, swapped-operand 32x32 MFMA, no max tracking ----------
// dbuf, 1 barrier/tile, zero-exchange P path, V slot order baked in layout,
// lsum via ones-MFMA, persistent zero C for QK t=0.
// FIX (r18): prefetch issue moved to AFTER __syncthreads -- hipcc emits
// vmcnt(0) before s_barrier, so issuing before the barrier synchronously
// drained the just-issued loads every tile (r10 regression, now isolated).
// Issued after the barrier, loads fly across the whole compute phase and
// drain at the next tile's LDS-write use.

__global__ __launch_bounds__(256) void attn_kernel(
    const u16* __restrict__ Qb, const u16* __restrict__ Kb,
    const u16* __restrict__ Vt, u16* __restrict__ ctx) {
  __shared__ __align__(16) u16 Kl[2][64][72];   // [buf][s][d], +8 pad
  __shared__ __align__(16) u16 Vl[2][64][72];   // [buf][d][s'], +8 pad

  const int bh = blockIdx.x;
  const int b = bh >> 4, h = bh & 15;
  const int qt = blockIdx.y;                 // 0..15
  const int tid = threadIdx.x, lane = tid & 63, w = tid >> 6;
  const int l32 = lane & 31, hi = lane >> 5;

  // Q B-fragments in registers: lane holds q-col (l32), d = 16t + 8hi + [0..8)
  bf16x8 qf[4];
  {
    size_t qrow = (size_t)(b * 2048 + qt * 128 + w * 32 + l32);
#pragma unroll
    for (int t = 0; t < 4; ++t)
      qf[t] = *(const bf16x8*)(Qb + qrow * D_MODEL + h * 64 + t * 16 + hi * 8);
  }

  // all-ones bf16 A-fragment for the lsum MFMA
  bf16x8 ones;
#pragma unroll
  for (int i = 0; i < 8; ++i) ones[i] = (short)0x3F80;

  const f32x16 zf = {0};        // persistent zero C-operand for QK t=0
  f32x16 o0 = {0}, o1 = {0};    // O^T accumulators: d-blocks [0,32) and [32,64)
  f32x16 la0 = {0}, la1 = {0};  // lsum accumulators (every element = row-sum)

  const u16* Kg = Kb + (size_t)b * 2048 * D_MODEL + h * 64;   // + s*1024 + d
  const u16* Vg = Vt + (size_t)(b * 1024 + h * 64) * 2048;    // + d*2048 + s'

  // staging: each thread owns 2 x 16B chunks per array
  const int r0 = tid >> 3,          c0 = (tid & 7) << 3;
  const int r1 = (tid + 256) >> 3,  c1 = c0;

  // T14 async-stage split: issue loads early, LDS-write late
  uint4 kreg0, kreg1, vreg0, vreg1;
  {
    kreg0 = *(const uint4*)(Kg + (size_t)r0 * D_MODEL + c0);
    kreg1 = *(const uint4*)(Kg + (size_t)r1 * D_MODEL + c1);
    vreg0 = *(const uint4*)(Vg + (size_t)r0 * 2048 + c0);
    vreg1 = *(const uint4*)(Vg + (size_t)r1 * 2048 + c1);
  }

  for (int it = 0; it < 32; ++it) {
    const int cur = it & 1;
    *(uint4*)&Kl[cur][r0][c0] = kreg0;
    *(uint4*)&Kl[cur][r1][c1] = kreg1;
    *(uint4*)&Vl[cur][r0][c0] = vreg0;
    *(uint4*)&Vl[cur][r1][c1] = vreg1;
    __syncthreads();   // single barrier per tile (vmcnt(0)+lgkmcnt(0) drain)

    // issue next tile's loads AFTER the barrier: they overlap the whole
    // compute phase below and drain at next tile's LDS-write use.
    if (it + 1 < 32) {
      int s0n = (it + 1) * 64;
      kreg0 = *(const uint4*)(Kg + (size_t)(s0n + r0) * D_MODEL + c0);
      kreg1 = *(const uint4*)(Kg + (size_t)(s0n + r1) * D_MODEL + c1);
      vreg0 = *(const uint4*)(Vg + (size_t)r0 * 2048 + s0n + c0);
      vreg1 = *(const uint4*)(Vg + (size_t)r1 * 2048 + s0n + c1);
    }

    // --- QK^T (swapped): two 32x32 S^T blocks over d = 4 x 16 ---
    f32x16 sa0, sa1;
    __builtin_amdgcn_s_setprio(1);
#pragma unroll
    for (int t = 0; t < 4; ++t) {
      bf16x8 kf0 = *(const bf16x8*)(&Kl[cur][l32][t * 16 + hi * 8]);
      bf16x8 kf1 = *(const bf16x8*)(&Kl[cur][32 + l32][t * 16 + hi * 8]);
      if (t == 0) {
        sa0 = __builtin_amdgcn_mfma_f32_32x32x16_bf16(kf0, qf[t], zf, 0, 0, 0);
        sa1 = __builtin_amdgcn_mfma_f32_32x32x16_bf16(kf1, qf[t], zf, 0, 0, 0);
      } else {
        sa0 = __builtin_amdgcn_mfma_f32_32x32x16_bf16(kf0, qf[t], sa0, 0, 0, 0);
        sa1 = __builtin_amdgcn_mfma_f32_32x32x16_bf16(kf1, qf[t], sa1, 0, 0, 0);
      }
    }
    __builtin_amdgcn_s_setprio(0);

    // --- softmax without max tracking: p = exp2(s) (raw v_exp_f32) ---
#pragma unroll
    for (int r = 0; r < 16; ++r) {
      sa0[r] = __builtin_amdgcn_exp2f(sa0[r]);
      sa1[r] = __builtin_amdgcn_exp2f(sa1[r]);
    }

    // --- PV (swapped), zero-exchange; V slot order baked into Vt layout;
    //     lsum rides along as ones-MFMA. ---
    __builtin_amdgcn_s_setprio(1);
#pragma unroll
    for (int t = 0; t < 4; ++t) {
      const f32x16& sa = (t < 2) ? sa0 : sa1;
      const int rb = 8 * (t & 1);
      u32x4 pw;
      pw[0] = cvtpk(sa[rb + 0], sa[rb + 1]);
      pw[1] = cvtpk(sa[rb + 2], sa[rb + 3]);
      pw[2] = cvtpk(sa[rb + 4], sa[rb + 5]);
      pw[3] = cvtpk(sa[rb + 6], sa[rb + 7]);
      bf16x8 pb = __builtin_bit_cast(bf16x8, pw);

      bf16x8 va0 = *(const bf16x8*)(&Vl[cur][l32][t * 16 + hi * 8]);
      bf16x8 va1 = *(const bf16x8*)(&Vl[cur][32 + l32][t * 16 + hi * 8]);

      o0 = __builtin_amdgcn_mfma_f32_32x32x16_bf16(va0, pb, o0, 0, 0, 0);
      o1 = __builtin_amdgcn_mfma_f32_32x32x16_bf16(va1, pb, o1, 0, 0, 0);
      if (t & 1) la1 = __builtin_amdgcn_mfma_f32_32x32x16_bf16(ones, pb, la1, 0, 0, 0);
      else       la0 = __builtin_amdgcn_mfma_f32_32x32x16_bf16(ones, pb, la0, 0, 0, 0);
    }
    __builtin_amdgcn_s_setprio(0);
  }

  // lsum: every element of la holds the full row-sum for q = l32.
  const float lsum = la0[0] + la1[0];
  const float inv = 1.0f / lsum;
  size_t row = (size_t)(b * 2048 + qt * 128 + w * 32 + l32);
  u16* cp = ctx + row * D_MODEL + h * 64;
#pragma unroll
  for (int rq = 0; rq < 4; ++rq) {
    int dbase = 8 * rq + 4 * hi;
    ushort4 pk;
    pk.x = f2bf(o0[4 * rq + 0] * inv);
    pk.y = f2bf(o0[4 * rq + 1] * inv);
    pk.z = f2bf(o0[4 * rq + 2] * inv);
    pk.w = f2bf(o0[4 * rq + 3] * inv);
    *(ushort4*)(cp + dbase) = pk;
    pk.x = f2bf(o1[4 * rq + 0] * inv);
    pk.y = f2bf(o1[4 * rq + 1] * inv);
    pk.z = f2bf(o1[4 * rq + 2] * inv);
    pk.w = f2bf(o1[4 * rq + 3] * inv);
    *(ushort4*)(cp + 32 + dbase) = pk;
  }
}

// ---- output projection: out = ctx @ Wo^T + bo (f32 out) --------------------

__global__ __launch_bounds__(256) void out_gemm(
    const u16* __restrict__ ctx, const u16* __restrict__ wo,
    const float* __restrict__ bo, float* __restrict__ out) {
  __shared__ __align__(16) u16 sA[2][128 * 64];
  __shared__ __align__(16) u16 sB[2][128 * 64];
  const int bid = (blockIdx.x & 7) * 32 + (blockIdx.x >> 3);   // 256%8==0
  const int mt = bid & 31, nt = bid >> 5;
  const int m0 = mt * 128, n0 = nt * 128;

  f32x4 acc[4][4];
#pragma unroll
  for (int mi = 0; mi < 4; ++mi)
#pragma unroll
    for (int ni = 0; ni < 4; ++ni)
      acc[mi][ni] = f32x4{0.f, 0.f, 0.f, 0.f};

  gemm_core_1024(ctx, wo, m0, n0, acc, sA, sB);

  const int lane = threadIdx.x & 63, wave = threadIdx.x >> 6;
  const int wr = wave >> 1, wc = wave & 1, l16 = lane & 15, lq = lane >> 4;
#pragma unroll
  for (int mi = 0; mi < 4; ++mi) {
#pragma unroll
    for (int ni = 0; ni < 4; ++ni) {
      int n = n0 + wc*64 + ni*16 + l16;
      float bz = bo[n];
      int mb = m0 + wr*64 + mi*16 + lq*4;
#pragma unroll
      for (int j = 0; j < 4; ++j)
        out[(size_t)(mb + j) * D_MODEL + n] = acc[mi][ni][j] + bz;
    }
  }
}

// ---- launcher --------------------------------------------------------------

extern "C" void kernel_launch(void* const* d_in, const int* in_sizes, int n_in,
                              void* d_out, int out_size, void* d_ws, size_t ws_size,
                              hipStream_t stream) {
  const float* query = (const float*)d_in[0];
  const float* key_  = (const float*)d_in[1];
  const float* value = (const float*)d_in[2];
  const float* Wq = (const float*)d_in[3];
  const float* bq = (const float*)d_in[4];
  const float* Wk = (const float*)d_in[5];
  const float* bk = (const float*)d_in[6];
  const float* Wv = (const float*)d_in[7];
  const float* bv = (const float*)d_in[8];
  const float* Wo = (const float*)d_in[9];
  const float* bo = (const float*)d_in[10];
  float* out = (float*)d_out;

  const size_t NX = (size_t)MM * D_MODEL;
  const size_t NW = (size_t)D_MODEL * D_MODEL;

  char* ws = (char*)d_ws;
  u16* xq  = (u16*)ws; ws += NX * 2;
  u16* xk  = (u16*)ws; ws += NX * 2;
  u16* xv  = (u16*)ws; ws += NX * 2;
  u16* wqb = (u16*)ws; ws += NW * 2;
  u16* wkb = (u16*)ws; ws += NW * 2;
  u16* wvb = (u16*)ws; ws += NW * 2;
  u16* wob = (u16*)ws; ws += NW * 2;
  u16* Qb  = (u16*)ws; ws += NX * 2;
  u16* Kb  = (u16*)ws; ws += NX * 2;
  u16* Vtb = (u16*)ws; ws += NX * 2;
  u16* ctx = (u16*)ws; ws += NX * 2;

  // one fused convert over all 7 f32 inputs (dsts contiguous from xq)
  const int n8 = 3 * NX8 + 4 * NW8;   // 2,097,152 chunks of 8
  cvt_all_kernel<<<2048, 256, 0, stream>>>(query, key_, value, Wq, Wk, Wv, Wo,
                                           xq, n8);

  qkv_gemm<<<768, 256, 0, stream>>>(xq, xk, xv, wqb, wkb, wvb, bq, bk, bv, Qb, Kb, Vtb);
  attn_kernel<<<dim3(32, 16), 256, 0, stream>>>(Qb, Kb, Vtb, ctx);
  out_gemm<<<256, 256, 0, stream>>>(ctx, wob, bo, out);
}

// Round 19
// 128.260 us; speedup vs baseline: 1.0073x; 1.0073x over previous
//
#include <hip/hip_runtime.h>
#include <hip/hip_bf16.h>
#include <cstdint>
#include <cstddef>

#define D_MODEL 1024
#define NHEADS  16
#define HDIM    64
#define BB      2
#define TT      2048
#define MM      (BB*TT)   // 4096 rows total

typedef __attribute__((ext_vector_type(8)))  short    bf16x8;
typedef __attribute__((ext_vector_type(4)))  float    f32x4;
typedef __attribute__((ext_vector_type(16))) float    f32x16;
typedef __attribute__((ext_vector_type(4)))  unsigned u32x4;
typedef unsigned short u16;

// fold 1/sqrt(64) * log2(e) into Q so softmax is p = exp2(s) directly
#define QSCALE 0.1803368801111204f

// ---- helpers ---------------------------------------------------------------

static __device__ __forceinline__ u16 f2bf(float f) {
  unsigned u = __builtin_bit_cast(unsigned, f);
  return (u16)((u + 0x7FFFu + ((u >> 16) & 1u)) >> 16);
}

static __device__ __forceinline__ void async16(const void* g, void* l) {
  __builtin_amdgcn_global_load_lds(
      (__attribute__((address_space(1))) void*)g,
      (__attribute__((address_space(3))) void*)l, 16, 0, 0);
}

// packed f32x2 -> bf16x2 (RNE), low word = first arg (compiler-lowered)
static __device__ __forceinline__ unsigned cvtpk(float lo, float hi) {
  __hip_bfloat162 h = __float22bfloat162_rn(float2{lo, hi});
  unsigned r;
  __builtin_memcpy(&r, &h, 4);
  return r;
}

// ---- fused f32 -> bf16 convert over all 7 inputs (one launch) --------------

#define NX8 (524288)   // NX/8
#define NW8 (131072)   // NW/8

__global__ __launch_bounds__(256) void cvt_all_kernel(
    const float* __restrict__ q, const float* __restrict__ k,
    const float* __restrict__ v, const float* __restrict__ wq,
    const float* __restrict__ wk, const float* __restrict__ wv,
    const float* __restrict__ wo, u16* __restrict__ dst, int n8) {
  int i = blockIdx.x * 256 + threadIdx.x;
  int stride = gridDim.x * 256;
  for (; i < n8; i += stride) {
    size_t j = (size_t)i;
    const float* s;
    if (j < NX8)            { s = q; }
    else if (j < 2 * NX8)   { s = k;  j -= NX8; }
    else if (j < 3 * NX8)   { s = v;  j -= 2 * (size_t)NX8; }
    else {
      j -= 3 * (size_t)NX8;
      if (j < NW8)          { s = wq; }
      else if (j < 2 * NW8) { s = wk; j -= NW8; }
      else if (j < 3 * NW8) { s = wv; j -= 2 * (size_t)NW8; }
      else                  { s = wo; j -= 3 * (size_t)NW8; }
    }
    float4 a = ((const float4*)s)[2 * j];
    float4 b = ((const float4*)s)[2 * j + 1];
    ushort4 ra, rb;
    ra.x = f2bf(a.x); ra.y = f2bf(a.y); ra.z = f2bf(a.z); ra.w = f2bf(a.w);
    rb.x = f2bf(b.x); rb.y = f2bf(b.y); rb.z = f2bf(b.z); rb.w = f2bf(b.w);
    ((ushort4*)dst)[2 * (size_t)i]     = ra;
    ((ushort4*)dst)[2 * (size_t)i + 1] = rb;
  }
}

// ---- GEMM core: C[128,128] tile of A[M,K] * W[N,K]^T (bf16, fp32 acc) ------
// r15 structure (best known): BK=64 dbuf, prefetch-before-MFMA, ONE barrier
// per K-step, T2 XOR-swizzle via pre-swizzled global source (rule #21-safe).

static __device__ __forceinline__ void gemm_core_1024(
    const u16* __restrict__ A, const u16* __restrict__ W,
    int m0, int n0, f32x4 acc[4][4],
    u16 (*__restrict__ sA)[128 * 64], u16 (*__restrict__ sB)[128 * 64]) {
  const int tid  = threadIdx.x;
  const int lane = tid & 63;
  const int wave = tid >> 6;
  const int wr = wave >> 1, wc = wave & 1;
  const int l16 = lane & 15, lq = lane >> 4;
  const int sx  = l16 & 7;                     // read-side row&7

  int rowi[4], cof[4];
#pragma unroll
  for (int i = 0; i < 4; ++i) {
    int idx = i * 256 + tid;
    rowi[i] = idx >> 3;
    cof[i]  = (((idx & 7) ^ (rowi[i] & 7)) << 3);   // u16 offset of 16B chunk
  }

  const int rc0 = ((0 * 4 + lq) ^ sx) << 3;
  const int rc1 = ((1 * 4 + lq) ^ sx) << 3;

  // prologue: stage K-tile 0 into buffer 0
#pragma unroll
  for (int i = 0; i < 4; ++i) {
    int idx = i * 256 + tid;
    async16(A + (size_t)(m0 + rowi[i]) * D_MODEL + cof[i], sA[0] + idx * 8);
    async16(W + (size_t)(n0 + rowi[i]) * D_MODEL + cof[i], sB[0] + idx * 8);
  }
  __syncthreads();   // vmcnt(0): buffer 0 ready

  int cur = 0;
  for (int k0 = 0; k0 < D_MODEL; k0 += 64) {
    if (k0 + 64 < D_MODEL) {
#pragma unroll
      for (int i = 0; i < 4; ++i) {
        int idx = i * 256 + tid;
        async16(A + (size_t)(m0 + rowi[i]) * D_MODEL + k0 + 64 + cof[i], sA[cur ^ 1] + idx * 8);
        async16(W + (size_t)(n0 + rowi[i]) * D_MODEL + k0 + 64 + cof[i], sB[cur ^ 1] + idx * 8);
      }
    }
    const u16* a_ = sA[cur];
    const u16* b_ = sB[cur];
#pragma unroll
    for (int ks = 0; ks < 2; ++ks) {
      const int rc = ks ? rc1 : rc0;
      bf16x8 af[4], bfr[4];
#pragma unroll
      for (int mi = 0; mi < 4; ++mi)
        af[mi] = *(const bf16x8*)(a_ + (wr*64 + mi*16 + l16)*64 + rc);
#pragma unroll
      for (int ni = 0; ni < 4; ++ni)
        bfr[ni] = *(const bf16x8*)(b_ + (wc*64 + ni*16 + l16)*64 + rc);
#pragma unroll
      for (int mi = 0; mi < 4; ++mi)
#pragma unroll
        for (int ni = 0; ni < 4; ++ni)
          acc[mi][ni] = __builtin_amdgcn_mfma_f32_16x16x32_bf16(
              af[mi], bfr[ni], acc[mi][ni], 0, 0, 0);
    }
    __syncthreads();
    cur ^= 1;
  }
}

// ---- fused QKV projection --------------------------------------------------
// Q gets QSCALE folded in. V written transposed [b][n][s'] with s' =
// swap-bits-2/3(s): bakes attn's PV slot order sigma into the layout so
// attn reads V fragments as single b128 (zero-exchange P path, no marshal).
// XCD-chunked swizzle (768 blocks, 96/XCD): W panels become L2-local (T1).

__global__ __launch_bounds__(256) void qkv_gemm(
    const u16* __restrict__ xq, const u16* __restrict__ xk, const u16* __restrict__ xv,
    const u16* __restrict__ wq, const u16* __restrict__ wk, const u16* __restrict__ wv,
    const float* __restrict__ bq, const float* __restrict__ bk, const float* __restrict__ bv,
    u16* __restrict__ Qo, u16* __restrict__ Ko, u16* __restrict__ Vt) {
  __shared__ __align__(16) u16 sA[2][128 * 64];
  __shared__ __align__(16) u16 sB[2][128 * 64];
  const int bid = (blockIdx.x & 7) * 96 + (blockIdx.x >> 3);   // bijective, 768%8==0
  const int mt = bid & 31, ct = bid >> 5;
  const int which = ct >> 3, nt = ct & 7;
  const u16* A = (which == 0) ? xq : (which == 1) ? xk : xv;
  const u16* W = (which == 0) ? wq : (which == 1) ? wk : wv;
  const float* bias = (which == 0) ? bq : (which == 1) ? bk : bv;
  const int m0 = mt * 128, n0 = nt * 128;

  f32x4 acc[4][4];
#pragma unroll
  for (int mi = 0; mi < 4; ++mi)
#pragma unroll
    for (int ni = 0; ni < 4; ++ni)
      acc[mi][ni] = f32x4{0.f, 0.f, 0.f, 0.f};

  gemm_core_1024(A, W, m0, n0, acc, sA, sB);

  const int lane = threadIdx.x & 63, wave = threadIdx.x >> 6;
  const int wr = wave >> 1, wc = wave & 1, l16 = lane & 15, lq = lane >> 4;
  const float qs = (which == 0) ? QSCALE : 1.0f;
#pragma unroll
  for (int mi = 0; mi < 4; ++mi) {
#pragma unroll
    for (int ni = 0; ni < 4; ++ni) {
      int n = n0 + wc*64 + ni*16 + l16;
      float bz = bias[n];
      int mb = m0 + wr*64 + mi*16 + lq*4;
      if (which == 2) {
        int b = mb >> 11, s = mb & 2047;
        int s2 = (s & ~0xC) | ((s & 4) << 1) | ((s & 8) >> 1);   // swap bits 2<->3
        ushort4 pk;
        pk.x = f2bf(acc[mi][ni][0] + bz);
        pk.y = f2bf(acc[mi][ni][1] + bz);
        pk.z = f2bf(acc[mi][ni][2] + bz);
        pk.w = f2bf(acc[mi][ni][3] + bz);
        *(ushort4*)(Vt + (size_t)(b * 1024 + n) * 2048 + s2) = pk;
      } else {
        u16* O = (which == 0) ? Qo : Ko;
#pragma unroll
        for (int j = 0; j < 4; ++j)
          O[(size_t)(mb + j) * D_MODEL + n] = f2bf((acc[mi][ni][j] + bz) * qs);
      }
    }
  }
}

// ---- flash attention, swapped-operand 32x32 MFMA, no max tracking ----------
// r17 exact (proven 55.9 us): dbuf, 1 barrier/tile, prefetch issued BEFORE
// the barrier (r18 falsified the after-barrier variant: -2 us), zero-exchange
// P path, V slot order baked in layout, lsum via ones-MFMA, persistent zero
// C for QK t=0.

__global__ __launch_bounds__(256) void attn_kernel(
    const u16* __restrict__ Qb, const u16* __restrict__ Kb,
    const u16* __restrict__ Vt, u16* __restrict__ ctx) {
  __shared__ __align__(16) u16 Kl[2][64][72];   // [buf][s][d], +8 pad
  __shared__ __align__(16) u16 Vl[2][64][72];   // [buf][d][s'], +8 pad

  const int bh = blockIdx.x;
  const int b = bh >> 4, h = bh & 15;
  const int qt = blockIdx.y;                 // 0..15
  const int tid = threadIdx.x, lane = tid & 63, w = tid >> 6;
  const int l32 = lane & 31, hi = lane >> 5;

  // Q B-fragments in registers: lane holds q-col (l32), d = 16t + 8hi + [0..8)
  bf16x8 qf[4];
  {
    size_t qrow = (size_t)(b * 2048 + qt * 128 + w * 32 + l32);
#pragma unroll
    for (int t = 0; t < 4; ++t)
      qf[t] = *(const bf16x8*)(Qb + qrow * D_MODEL + h * 64 + t * 16 + hi * 8);
  }

  // all-ones bf16 A-fragment for the lsum MFMA
  bf16x8 ones;
#pragma unroll
  for (int i = 0; i < 8; ++i) ones[i] = (short)0x3F80;

  const f32x16 zf = {0};        // persistent zero C-operand for QK t=0
  f32x16 o0 = {0}, o1 = {0};    // O^T accumulators: d-blocks [0,32) and [32,64)
  f32x16 la0 = {0}, la1 = {0};  // lsum accumulators (every element = row-sum)

  const u16* Kg = Kb + (size_t)b * 2048 * D_MODEL + h * 64;   // + s*1024 + d
  const u16* Vg = Vt + (size_t)(b * 1024 + h * 64) * 2048;    // + d*2048 + s'

  // staging: each thread owns 2 x 16B chunks per array
  const int r0 = tid >> 3,          c0 = (tid & 7) << 3;
  const int r1 = (tid + 256) >> 3,  c1 = c0;

  // T14 async-stage split: issue loads early, LDS-write late
  uint4 kreg0, kreg1, vreg0, vreg1;
  {
    kreg0 = *(const uint4*)(Kg + (size_t)r0 * D_MODEL + c0);
    kreg1 = *(const uint4*)(Kg + (size_t)r1 * D_MODEL + c1);
    vreg0 = *(const uint4*)(Vg + (size_t)r0 * 2048 + c0);
    vreg1 = *(const uint4*)(Vg + (size_t)r1 * 2048 + c1);
  }

  for (int it = 0; it < 32; ++it) {
    const int cur = it & 1;
    *(uint4*)&Kl[cur][r0][c0] = kreg0;
    *(uint4*)&Kl[cur][r1][c1] = kreg1;
    *(uint4*)&Vl[cur][r0][c0] = vreg0;
    *(uint4*)&Vl[cur][r1][c1] = vreg1;

    if (it + 1 < 32) {
      int s0n = (it + 1) * 64;
      kreg0 = *(const uint4*)(Kg + (size_t)(s0n + r0) * D_MODEL + c0);
      kreg1 = *(const uint4*)(Kg + (size_t)(s0n + r1) * D_MODEL + c1);
      vreg0 = *(const uint4*)(Vg + (size_t)r0 * 2048 + s0n + c0);
      vreg1 = *(const uint4*)(Vg + (size_t)r1 * 2048 + s0n + c1);
    }
    __syncthreads();   // single barrier per tile

    // --- QK^T (swapped): two 32x32 S^T blocks over d = 4 x 16 ---
    f32x16 sa0, sa1;
    __builtin_amdgcn_s_setprio(1);
#pragma unroll
    for (int t = 0; t < 4; ++t) {
      bf16x8 kf0 = *(const bf16x8*)(&Kl[cur][l32][t * 16 + hi * 8]);
      bf16x8 kf1 = *(const bf16x8*)(&Kl[cur][32 + l32][t * 16 + hi * 8]);
      if (t == 0) {
        sa0 = __builtin_amdgcn_mfma_f32_32x32x16_bf16(kf0, qf[t], zf, 0, 0, 0);
        sa1 = __builtin_amdgcn_mfma_f32_32x32x16_bf16(kf1, qf[t], zf, 0, 0, 0);
      } else {
        sa0 = __builtin_amdgcn_mfma_f32_32x32x16_bf16(kf0, qf[t], sa0, 0, 0, 0);
        sa1 = __builtin_amdgcn_mfma_f32_32x32x16_bf16(kf1, qf[t], sa1, 0, 0, 0);
      }
    }
    __builtin_amdgcn_s_setprio(0);

    // --- softmax without max tracking: p = exp2(s) (raw v_exp_f32) ---
#pragma unroll
    for (int r = 0; r < 16; ++r) {
      sa0[r] = __builtin_amdgcn_exp2f(sa0[r]);
      sa1[r] = __builtin_amdgcn_exp2f(sa1[r]);
    }

    // --- PV (swapped), zero-exchange; V slot order baked into Vt layout;
    //     lsum rides along as ones-MFMA. ---
    __builtin_amdgcn_s_setprio(1);
#pragma unroll
    for (int t = 0; t < 4; ++t) {
      const f32x16& sa = (t < 2) ? sa0 : sa1;
      const int rb = 8 * (t & 1);
      u32x4 pw;
      pw[0] = cvtpk(sa[rb + 0], sa[rb + 1]);
      pw[1] = cvtpk(sa[rb + 2], sa[rb + 3]);
      pw[2] = cvtpk(sa[rb + 4], sa[rb + 5]);
      pw[3] = cvtpk(sa[rb + 6], sa[rb + 7]);
      bf16x8 pb = __builtin_bit_cast(bf16x8, pw);

      bf16x8 va0 = *(const bf16x8*)(&Vl[cur][l32][t * 16 + hi * 8]);
      bf16x8 va1 = *(const bf16x8*)(&Vl[cur][32 + l32][t * 16 + hi * 8]);

      o0 = __builtin_amdgcn_mfma_f32_32x32x16_bf16(va0, pb, o0, 0, 0, 0);
      o1 = __builtin_amdgcn_mfma_f32_32x32x16_bf16(va1, pb, o1, 0, 0, 0);
      if (t & 1) la1 = __builtin_amdgcn_mfma_f32_32x32x16_bf16(ones, pb, la1, 0, 0, 0);
      else       la0 = __builtin_amdgcn_mfma_f32_32x32x16_bf16(ones, pb, la0, 0, 0, 0);
    }
    __builtin_amdgcn_s_setprio(0);
  }

  // lsum: every element of la holds the full row-sum for q = l32.
  const float lsum = la0[0] + la1[0];
  const float inv = 1.0f / lsum;
  size_t row = (size_t)(b * 2048 + qt * 128 + w * 32 + l32);
  u16* cp = ctx + row * D_MODEL + h * 64;
#pragma unroll
  for (int rq = 0; rq < 4; ++rq) {
    int dbase = 8 * rq + 4 * hi;
    ushort4 pk;
    pk.x = f2bf(o0[4 * rq + 0] * inv);
    pk.y = f2bf(o0[4 * rq + 1] * inv);
    pk.z = f2bf(o0[4 * rq + 2] * inv);
    pk.w = f2bf(o0[4 * rq + 3] * inv);
    *(ushort4*)(cp + dbase) = pk;
    pk.x = f2bf(o1[4 * rq + 0] * inv);
    pk.y = f2bf(o1[4 * rq + 1] * inv);
    pk.z = f2bf(o1[4 * rq + 2] * inv);
    pk.w = f2bf(o1[4 * rq + 3] * inv);
    *(ushort4*)(cp + 32 + dbase) = pk;
  }
}

// ---- output projection: out = ctx @ Wo^T + bo (f32 out) --------------------

__global__ __launch_bounds__(256) void out_gemm(
    const u16* __restrict__ ctx, const u16* __restrict__ wo,
    const float* __restrict__ bo, float* __restrict__ out) {
  __shared__ __align__(16) u16 sA[2][128 * 64];
  __shared__ __align__(16) u16 sB[2][128 * 64];
  const int bid = (blockIdx.x & 7) * 32 + (blockIdx.x >> 3);   // 256%8==0
  const int mt = bid & 31, nt = bid >> 5;
  const int m0 = mt * 128, n0 = nt * 128;

  f32x4 acc[4][4];
#pragma unroll
  for (int mi = 0; mi < 4; ++mi)
#pragma unroll
    for (int ni = 0; ni < 4; ++ni)
      acc[mi][ni] = f32x4{0.f, 0.f, 0.f, 0.f};

  gemm_core_1024(ctx, wo, m0, n0, acc, sA, sB);

  const int lane = threadIdx.x & 63, wave = threadIdx.x >> 6;
  const int wr = wave >> 1, wc = wave & 1, l16 = lane & 15, lq = lane >> 4;
#pragma unroll
  for (int mi = 0; mi < 4; ++mi) {
#pragma unroll
    for (int ni = 0; ni < 4; ++ni) {
      int n = n0 + wc*64 + ni*16 + l16;
      float bz = bo[n];
      int mb = m0 + wr*64 + mi*16 + lq*4;
#pragma unroll
      for (int j = 0; j < 4; ++j)
        out[(size_t)(mb + j) * D_MODEL + n] = acc[mi][ni][j] + bz;
    }
  }
}

// ---- launcher --------------------------------------------------------------

extern "C" void kernel_launch(void* const* d_in, const int* in_sizes, int n_in,
                              void* d_out, int out_size, void* d_ws, size_t ws_size,
                              hipStream_t stream) {
  const float* query = (const float*)d_in[0];
  const float* key_  = (const float*)d_in[1];
  const float* value = (const float*)d_in[2];
  const float* Wq = (const float*)d_in[3];
  const float* bq = (const float*)d_in[4];
  const float* Wk = (const float*)d_in[5];
  const float* bk = (const float*)d_in[6];
  const float* Wv = (const float*)d_in[7];
  const float* bv = (const float*)d_in[8];
  const float* Wo = (const float*)d_in[9];
  const float* bo = (const float*)d_in[10];
  float* out = (float*)d_out;

  const size_t NX = (size_t)MM * D_MODEL;
  const size_t NW = (size_t)D_MODEL * D_MODEL;

  char* ws = (char*)d_ws;
  u16* xq  = (u16*)ws; ws += NX * 2;
  u16* xk  = (u16*)ws; ws += NX * 2;
  u16* xv  = (u16*)ws; ws += NX * 2;
  u16* wqb = (u16*)ws; ws += NW * 2;
  u16* wkb = (u16*)ws; ws += NW * 2;
  u16* wvb = (u16*)ws; ws += NW * 2;
  u16* wob = (u16*)ws; ws += NW * 2;
  u16* Qb  = (u16*)ws; ws += NX * 2;
  u16* Kb  = (u16*)ws; ws += NX * 2;
  u16* Vtb = (u16*)ws; ws += NX * 2;
  u16* ctx = (u16*)ws; ws += NX * 2;

  // one fused convert over all 7 f32 inputs (dsts contiguous from xq)
  const int n8 = 3 * NX8 + 4 * NW8;   // 2,097,152 chunks of 8
  cvt_all_kernel<<<2048, 256, 0, stream>>>(query, key_, value, Wq, Wk, Wv, Wo,
                                           xq, n8);

  qkv_gemm<<<768, 256, 0, stream>>>(xq, xk, xv, wqb, wkb, wvb, bq, bk, bv, Qb, Kb, Vtb);
  attn_kernel<<<dim3(32, 16), 256, 0, stream>>>(Qb, Kb, Vtb, ctx);
  out_gemm<<<256, 256, 0, stream>>>(ctx, wob, bo, out);
}